// Round 12
// baseline (128.871 us; speedup 1.0000x reference)
//
#include <hip/hip_runtime.h>
#include <hip/hip_bf16.h>
#include <math.h>

#define NB 4
#define NC 64
#define NH 48
#define NW 48
#define NHEADS 4
#define NCH 256
#define NHW 2304
#define NBH 16
#define NCHK 4
#define CHUNK 576
#define NT (CHUNK / 32)

// ws byte offsets. G+SQ [0,532480) used qkv->scale; OHp [0,18.9MB) used attn->proj.
#define OB_G    0ull
#define OB_SQ   524288ull
#define OB_OHP  0ull
#define OB_Q    18874368ull
#define OB_K    23592960ull
#define OB_V    28311552ull
#define OB_L    33030144ull
#define OB_SC   33619968ull

typedef __bf16 bf16x8 __attribute__((ext_vector_type(8)));
typedef float f32x4 __attribute__((ext_vector_type(4)));
typedef float f32x16 __attribute__((ext_vector_type(16)));

__device__ __forceinline__ float bf2f(ushort u) {
  return __uint_as_float(((unsigned)u) << 16);
}
__device__ __forceinline__ ushort f2bf(float f) {
  __hip_bfloat16 h = __float2bfloat16(f);
  return *(ushort*)&h;
}
__device__ __forceinline__ void gload16(const void* g, void* l) {
  __builtin_amdgcn_global_load_lds((const __attribute__((address_space(1))) unsigned int*)g,
                                   (__attribute__((address_space(3))) unsigned int*)l, 16, 0, 0);
}

// ================= fused LN + 1x1conv + dw3x3 + L2norm + gram =================
// grid (48, 12, NB): blockIdx.y = hd + 4*qkv. 256 thr. LDS pool (time-shared):
//  A [0,39168):    Xs f32[144][68]  ->  Yl bf16[64][148]  ->  Tb bf16 swz[64][64]
//  B [39168,57600): Xb bf16 swz[144][64]  ->  Zs f32[64][50] + Rp + Rs
//  C [57600,61952): Ks9 f32[64][9], mu/rs[144], lw/lb[64]
#define PO_XB 39168
#define PO_ZS 39168
#define PO_RP 52768
#define PO_RS 53536
#define PO_K9 57600
#define PO_MU 59904
#define PO_RSD 60480
#define PO_LW 61056
#define PO_LB 61312
__global__ __launch_bounds__(256) void k_qkv(const float* __restrict__ emb,
                                             const float* __restrict__ lw,
                                             const float* __restrict__ lb,
                                             const float* __restrict__ wq,
                                             const float* __restrict__ wk,
                                             const float* __restrict__ wv,
                                             const float* __restrict__ dwq,
                                             const float* __restrict__ dwk,
                                             const float* __restrict__ dwv,
                                             ushort* __restrict__ Qo,
                                             ushort* __restrict__ Ko,
                                             ushort* __restrict__ Vo,
                                             float* __restrict__ G,
                                             float* __restrict__ SQ) {
  __shared__ __align__(16) char pool[61952];
  float* Xs = (float*)pool;                      // [p][68]
  ushort* Yl = (ushort*)pool;                    // [c][148]
  float* Zs = (float*)(pool + PO_ZS);            // [c][50]
  float* Rp = (float*)(pool + PO_RP);            // [4][48]
  float* Rs = (float*)(pool + PO_RS);            // [48]
  float* Ks9 = (float*)(pool + PO_K9);           // [c][9]
  float* mu_s = (float*)(pool + PO_MU);
  float* rs_s = (float*)(pool + PO_RSD);
  float* lw_s = (float*)(pool + PO_LW);
  float* lb_s = (float*)(pool + PO_LB);

  int h = blockIdx.x;
  int hd = blockIdx.y & 3, qkv = blockIdx.y >> 2;
  int b = blockIdx.z;
  int bh = b * NHEADS + hd;
  const float* Wm = qkv == 0 ? wq : (qkv == 1 ? wk : wv);
  const float* dwp = qkv == 0 ? dwq : (qkv == 1 ? dwk : dwv);
  int t = threadIdx.x, lane = t & 63, wvi = t >> 6;
  int l15 = lane & 15, l4 = lane >> 4;

  // phase 1: emb rows h-1..h+1 -> Xs[p=r*48+w][c] (zeros out of range); lw/lb; Ks9
  for (int e = t; e < 2304; e += 256) {
    int c = e / 36, rem = e % 36, r = rem / 12, w4 = (rem % 12) * 4;
    int hh = h + r - 1;
    float4 v = (hh >= 0 && hh < NH) ? *(const float4*)&emb[((size_t)b * NC + c) * NHW + hh * NW + w4]
                                    : make_float4(0.f, 0.f, 0.f, 0.f);
    int p = r * 48 + w4;
    Xs[p * 68 + c] = v.x;
    Xs[(p + 1) * 68 + c] = v.y;
    Xs[(p + 2) * 68 + c] = v.z;
    Xs[(p + 3) * 68 + c] = v.w;
  }
  if (t < 64) { lw_s[t] = lw[t]; lb_s[t] = lb[t]; }
  for (int e = t; e < 576; e += 256) Ks9[e] = dwp[(size_t)hd * 576 + e];
  __syncthreads();
  // phase 2: LN stats per px
  if (t < 144) {
    float s = 0.f, ss = 0.f;
#pragma unroll
    for (int c = 0; c < 64; c += 4) {
      float4 v = *(const float4*)&Xs[t * 68 + c];
      s += (v.x + v.y) + (v.z + v.w);
      ss += (v.x * v.x + v.y * v.y) + (v.z * v.z + v.w * v.w);
    }
    float m = s * (1.f / 64.f), va = ss * (1.f / 64.f) - m * m;
    mu_s[t] = m;
    rs_s[t] = rsqrtf(va + 1e-5f);
  }
  __syncthreads();
  // phase 3: Xb bf16 [px][c], 16B-chunk XOR swizzle (chunk' = (c8>>3) ^ (px&7))
  for (int e = t; e < 1152; e += 256) {
    int px = e >> 3, c8 = (e & 7) * 8;
    int chunk = (c8 >> 3) ^ (px & 7);
    float mu = mu_s[px], rs = rs_s[px];
    float4 v0 = *(const float4*)&Xs[px * 68 + c8];
    float4 v1 = *(const float4*)&Xs[px * 68 + c8 + 4];
    union { bf16x8 v; ushort u[8]; } pk;
    pk.u[0] = f2bf((v0.x - mu) * rs * lw_s[c8] + lb_s[c8]);
    pk.u[1] = f2bf((v0.y - mu) * rs * lw_s[c8 + 1] + lb_s[c8 + 1]);
    pk.u[2] = f2bf((v0.z - mu) * rs * lw_s[c8 + 2] + lb_s[c8 + 2]);
    pk.u[3] = f2bf((v0.w - mu) * rs * lw_s[c8 + 3] + lb_s[c8 + 3]);
    pk.u[4] = f2bf((v1.x - mu) * rs * lw_s[c8 + 4] + lb_s[c8 + 4]);
    pk.u[5] = f2bf((v1.y - mu) * rs * lw_s[c8 + 5] + lb_s[c8 + 5]);
    pk.u[6] = f2bf((v1.z - mu) * rs * lw_s[c8 + 6] + lb_s[c8 + 6]);
    pk.u[7] = f2bf((v1.w - mu) * rs * lw_s[c8 + 7] + lb_s[c8 + 7]);
    *(bf16x8*)(pool + PO_XB + px * 128 + chunk * 16) = pk.v;
  }
  __syncthreads();
  // phase 4: GEMM 64x144x64; wave w -> out-chs [16w,16w+16) x 144 px; write Yl
  {
    bf16x8 afr[2];
    const float* wr = Wm + (size_t)(hd * 64 + wvi * 16 + l15) * 64;
#pragma unroll
    for (int kc = 0; kc < 2; ++kc) {
      float4 w0 = *(const float4*)&wr[kc * 32 + l4 * 8];
      float4 w1 = *(const float4*)&wr[kc * 32 + l4 * 8 + 4];
      union { bf16x8 v; ushort u[8]; } pk;
      pk.u[0] = f2bf(w0.x); pk.u[1] = f2bf(w0.y); pk.u[2] = f2bf(w0.z); pk.u[3] = f2bf(w0.w);
      pk.u[4] = f2bf(w1.x); pk.u[5] = f2bf(w1.y); pk.u[6] = f2bf(w1.z); pk.u[7] = f2bf(w1.w);
      afr[kc] = pk.v;
    }
    f32x4 acc[9];
#pragma unroll
    for (int i = 0; i < 9; ++i) acc[i] = (f32x4){0.f, 0.f, 0.f, 0.f};
#pragma unroll
    for (int pxt = 0; pxt < 9; ++pxt) {
      int px = pxt * 16 + l15;
#pragma unroll
      for (int kc = 0; kc < 2; ++kc) {
        int chunk = (kc * 4 + l4) ^ (px & 7);
        bf16x8 bfr = *(const bf16x8*)(pool + PO_XB + px * 128 + chunk * 16);
        acc[pxt] = __builtin_amdgcn_mfma_f32_16x16x32_bf16(afr[kc], bfr, acc[pxt], 0, 0, 0);
      }
    }
    __syncthreads();   // Xs dead; Yl overlays region A
#pragma unroll
    for (int pxt = 0; pxt < 9; ++pxt)
#pragma unroll
      for (int r = 0; r < 4; ++r)
        Yl[(wvi * 16 + l4 * 4 + r) * 148 + pxt * 16 + l15] = f2bf(acc[pxt][r]);
  }
  __syncthreads();
  // phase 5: depthwise 3x3 from Yl (row-validity guard) -> Zs
  for (int e = t; e < 768; e += 256) {
    int c = e / 12, w4 = (e % 12) * 4;
    float acc0 = 0.f, acc1 = 0.f, acc2 = 0.f, acc3 = 0.f;
#pragma unroll
    for (int r = 0; r < 3; ++r) {
      bool rOK = (unsigned)(h + r - 1) < (unsigned)NH;
      const ushort* row = &Yl[c * 148 + r * 48];
      int li = w4 >= 4 ? w4 - 4 : 0;
      int ri = w4 <= 40 ? w4 + 4 : 40;
      uint2 L = *(const uint2*)&row[li];
      uint2 M = *(const uint2*)&row[w4];
      uint2 R = *(const uint2*)&row[ri];
      float vm1 = (w4 == 0) ? 0.f : __uint_as_float(L.y & 0xffff0000u);
      float m0 = __uint_as_float(M.x << 16);
      float m1 = __uint_as_float(M.x & 0xffff0000u);
      float m2 = __uint_as_float(M.y << 16);
      float m3 = __uint_as_float(M.y & 0xffff0000u);
      float v4 = (w4 == 44) ? 0.f : __uint_as_float(R.x << 16);
      float k0 = rOK ? Ks9[c * 9 + r * 3] : 0.f;
      float k1 = rOK ? Ks9[c * 9 + r * 3 + 1] : 0.f;
      float k2 = rOK ? Ks9[c * 9 + r * 3 + 2] : 0.f;
      acc0 += vm1 * k0 + m0 * k1 + m1 * k2;
      acc1 += m0 * k0 + m1 * k1 + m2 * k2;
      acc2 += m1 * k0 + m2 * k1 + m3 * k2;
      acc3 += m2 * k0 + m3 * k1 + v4 * k2;
    }
    *(float2*)&Zs[c * 50 + w4] = make_float2(acc0, acc1);
    *(float2*)&Zs[c * 50 + w4 + 2] = make_float2(acc2, acc3);
  }
  __syncthreads();
  if (qkv < 2) {
    if (t < 192) {
      int cq = t / 48, w = t % 48;
      float ss = 0.f;
#pragma unroll
      for (int i = 0; i < 16; ++i) { float z = Zs[(cq * 16 + i) * 50 + w]; ss += z * z; }
      Rp[cq * 48 + w] = ss;
    }
    __syncthreads();
    if (t < 48)
      Rs[t] = 1.f / fmaxf(sqrtf(Rp[t] + Rp[48 + t] + Rp[96 + t] + Rp[144 + t]), 1e-12f);
    __syncthreads();
    // global write + Tb build (Tb overlays Yl, dead after phase 5's barrier chain)
    ushort* dst = (qkv == 0 ? Qo : Ko) + (size_t)bh * NHW * 64;
    for (int e = t; e < 768; e += 256) {
      int w = e >> 4, c4 = (e & 15) * 4;
      float rsc = Rs[w];
      ushort4 u = make_ushort4(f2bf(Zs[c4 * 50 + w] * rsc), f2bf(Zs[(c4 + 1) * 50 + w] * rsc),
                               f2bf(Zs[(c4 + 2) * 50 + w] * rsc), f2bf(Zs[(c4 + 3) * 50 + w] * rsc));
      *(ushort4*)&dst[((size_t)(c4 >> 3) * NHW + h * NW + w) * 8 + (c4 & 7)] = u;
    }
    for (int e = t; e < 384; e += 256) {   // Tb[c][n] bf16 swizzled, n 0..47
      int c = e / 6, n8 = (e % 6) * 8;
      int chunk = (n8 >> 3) ^ (c & 7);
      union { bf16x8 v; ushort u[8]; } pk;
#pragma unroll
      for (int j = 0; j < 8; ++j) pk.u[j] = f2bf(Zs[c * 50 + n8 + j] * Rs[n8 + j]);
      *(bf16x8*)(pool + c * 128 + chunk * 16) = pk.v;
    }
    for (int e = t; e < 128; e += 256) {   // zero pad n 48..63
      int c = e >> 1, ch = 6 + (e & 1);
      int chunk = ch ^ (c & 7);
      *(bf16x8*)(pool + c * 128 + chunk * 16) = (bf16x8){};
    }
    __syncthreads();
    // local gram 64x64 over 48 rows via MFMA; atomic accumulate
    {
      int ci0 = wvi * 16;
      bf16x8 a[2];
#pragma unroll
      for (int kc = 0; kc < 2; ++kc) {
        int row = ci0 + l15;
        int chunk = (kc * 4 + l4) ^ (row & 7);
        a[kc] = *(const bf16x8*)(pool + row * 128 + chunk * 16);
      }
      f32x4 g[4];
#pragma unroll
      for (int i = 0; i < 4; ++i) g[i] = (f32x4){0.f, 0.f, 0.f, 0.f};
#pragma unroll
      for (int cj = 0; cj < 4; ++cj) {
        int row = cj * 16 + l15;
#pragma unroll
        for (int kc = 0; kc < 2; ++kc) {
          int chunk = (kc * 4 + l4) ^ (row & 7);
          bf16x8 bb = *(const bf16x8*)(pool + row * 128 + chunk * 16);
          g[cj] = __builtin_amdgcn_mfma_f32_16x16x32_bf16(a[kc], bb, g[cj], 0, 0, 0);
        }
      }
      float* gdst = G + ((size_t)qkv * NBH + bh) * 4096;
#pragma unroll
      for (int cj = 0; cj < 4; ++cj)
#pragma unroll
        for (int r = 0; r < 4; ++r)
          atomicAdd(&gdst[(ci0 + l4 * 4 + r) * 64 + cj * 16 + l15], g[cj][r]);
    }
    if (t < 64) {
      float s = 0.f;
      for (int w = 0; w < 48; ++w) s += bf2f(f2bf(Zs[t * 50 + w] * Rs[w]));
      atomicAdd(&SQ[((size_t)qkv * NBH + bh) * 64 + t], s);
    }
  } else {
    ushort* dst = Vo + (size_t)bh * NHW * 64;
    for (int e = t; e < 768; e += 256) {
      int c = e / 12, w4 = (e % 12) * 4;
      float4 z = *(const float4*)&Zs[c * 50 + w4];
      ushort4 u = make_ushort4(f2bf(z.x), f2bf(z.y), f2bf(z.z), f2bf(z.w));
      *(ushort4*)&dst[((size_t)(h * 6 + (w4 >> 3)) * 64 + c) * 8 + (w4 & 7)] = u;
    }
  }
}

// ---------------- per-(b,h) exp2 scale (single accumulated G) ----------------
__global__ __launch_bounds__(256) void k_scale(const float* __restrict__ G,
                                               const float* __restrict__ SQ,
                                               float* __restrict__ SC) {
  __shared__ float red[256];
  int bh = blockIdx.x, t = threadIdx.x;
  float ssum = 0.f;
  for (int i = t; i < 4096; i += 256)
    ssum += G[(size_t)bh * 4096 + i] * G[(size_t)(NBH + bh) * 4096 + i];
  red[t] = ssum;
  __syncthreads();
  if (t < 128) red[t] += red[t + 128];
  __syncthreads();
  if (t < 64) {
    float v = red[t] + red[t + 64];
    float v2 = SQ[bh * 64 + t] * SQ[(NBH + bh) * 64 + t];
#pragma unroll
    for (int m = 32; m; m >>= 1) { v += __shfl_xor(v, m); v2 += __shfl_xor(v2, m); }
    if (t == 0) {
      const double N2 = (double)NHW * (double)NHW;
      double mean = (double)v2 / (N2 * 48.0);
      double ea2 = (double)v / (N2 * 2304.0);
      double var = ea2 - mean * mean;
      SC[bh] = (float)((1.0 / sqrt(var + 1e-5)) / 48.0 * 1.4426950408889634);
    }
  }
}

// ---------------- flash attention (round-8 config: best measured) ----------------
__global__ __launch_bounds__(256, 2) void k_attn(const ushort* __restrict__ Q,
                                                 const ushort* __restrict__ K,
                                                 const ushort* __restrict__ V,
                                                 const float* __restrict__ SC,
                                                 ushort* __restrict__ OHp,
                                                 float* __restrict__ Lp) {
  __shared__ ushort Kl[4][2048];
  __shared__ ushort Vl[4][2048];
  int p = blockIdx.x;
  int gb = p & 7;
  int w = p >> 3;          // 0..143
  int qt = w % 18;
  int rem = w / 18;        // 0..7
  int chunk = rem & 3;
  int bh = gb * 2 + (rem >> 2);
  int t = threadIdx.x, lane = t & 63, wv = t >> 6;
  int ql = lane & 31, h = lane >> 5;
  int q0 = qt * 128 + wv * 32;
  int m00 = chunk * CHUNK;
  const ushort* base = Q + (size_t)bh * NHW * 64;
  float sc2 = SC[bh];

  bf16x8 qfr[4];
#pragma unroll
  for (int kc = 0; kc < 4; ++kc)
    qfr[kc] = *(const bf16x8*)&base[((size_t)(kc * 2 + h) * NHW + q0 + ql) * 8];
  asm volatile("s_waitcnt vmcnt(0)" ::: "memory");

  const ushort* kst = K + (size_t)bh * NHW * 64 + ((size_t)(wv * 2 + h) * NHW + m00 + ql) * 8;
  const ushort* vst = V + (size_t)bh * NHW * 64 + ((size_t)((m00 >> 3) + wv) * 64 + lane) * 8;

  f32x16 o0 = {}, o1 = {};
  float lp = 0.f;

  auto COMPUTE = [&](int cb) {
    bf16x8 ka[4], vb[4];
#pragma unroll
    for (int i = 0; i < 4; ++i)
      ka[i] = *(const bf16x8*)&Kl[cb][(2 * i + h) * 256 + ql * 8];
    vb[0] = *(const bf16x8*)&Vl[cb][h * 512 + ql * 8];
    vb[1] = *(const bf16x8*)&Vl[cb][(2 + h) * 512 + ql * 8];
    vb[2] = *(const bf16x8*)&Vl[cb][h * 512 + (ql + 32) * 8];
    vb[3] = *(const bf16x8*)&Vl[cb][(2 + h) * 512 + (ql + 32) * 8];
    __builtin_amdgcn_s_setprio(1);
    f32x16 s = {};
    s = __builtin_amdgcn_mfma_f32_32x32x16_bf16(ka[0], qfr[0], s, 0, 0, 0);
    s = __builtin_amdgcn_mfma_f32_32x32x16_bf16(ka[1], qfr[1], s, 0, 0, 0);
    s = __builtin_amdgcn_mfma_f32_32x32x16_bf16(ka[2], qfr[2], s, 0, 0, 0);
    s = __builtin_amdgcn_mfma_f32_32x32x16_bf16(ka[3], qfr[3], s, 0, 0, 0);
    __builtin_amdgcn_s_setprio(0);
    float pv[16];
    float l0 = 0.f, l1 = 0.f, l2 = 0.f, l3 = 0.f;
#pragma unroll
    for (int r = 0; r < 16; r += 4) {
      pv[r] = __builtin_exp2f(s[r] * sc2);
      pv[r + 1] = __builtin_exp2f(s[r + 1] * sc2);
      pv[r + 2] = __builtin_exp2f(s[r + 2] * sc2);
      pv[r + 3] = __builtin_exp2f(s[r + 3] * sc2);
      l0 += pv[r]; l1 += pv[r + 1]; l2 += pv[r + 2]; l3 += pv[r + 3];
    }
    lp += (l0 + l1) + (l2 + l3);
    uint u[8];
#pragma unroll
    for (int i = 0; i < 8; ++i)
      asm("v_cvt_pk_bf16_f32 %0, %1, %2" : "=v"(u[i]) : "v"(pv[2 * i]), "v"(pv[2 * i + 1]));
    asm volatile("v_permlane32_swap_b32 %0, %1" : "+v"(u[0]), "+v"(u[2]));
    asm volatile("v_permlane32_swap_b32 %0, %1" : "+v"(u[1]), "+v"(u[3]));
    asm volatile("v_permlane32_swap_b32 %0, %1" : "+v"(u[4]), "+v"(u[6]));
    asm volatile("v_permlane32_swap_b32 %0, %1" : "+v"(u[5]), "+v"(u[7]));
    union { uint uu[4]; bf16x8 v; } pa0, pa1;
    pa0.uu[0] = u[0]; pa0.uu[1] = u[1]; pa0.uu[2] = u[2]; pa0.uu[3] = u[3];
    pa1.uu[0] = u[4]; pa1.uu[1] = u[5]; pa1.uu[2] = u[6]; pa1.uu[3] = u[7];
    __builtin_amdgcn_s_setprio(1);
    o0 = __builtin_amdgcn_mfma_f32_32x32x16_bf16(pa0.v, vb[0], o0, 0, 0, 0);
    o0 = __builtin_amdgcn_mfma_f32_32x32x16_bf16(pa1.v, vb[1], o0, 0, 0, 0);
    o1 = __builtin_amdgcn_mfma_f32_32x32x16_bf16(pa0.v, vb[2], o1, 0, 0, 0);
    o1 = __builtin_amdgcn_mfma_f32_32x32x16_bf16(pa1.v, vb[3], o1, 0, 0, 0);
    __builtin_amdgcn_s_setprio(0);
  };

  gload16(kst, (void*)&Kl[0][wv * 512]);
  gload16(vst, (void*)&Vl[0][wv * 512]);
  gload16(kst + 256, (void*)&Kl[1][wv * 512]);
  gload16(vst + 2048, (void*)&Vl[1][wv * 512]);

  for (int mt = 0; mt < NT - 2; ++mt) {
    int sb = (mt + 2) & 3;
    gload16(kst + (size_t)(mt + 2) * 256, (void*)&Kl[sb][wv * 512]);
    gload16(vst + (size_t)(mt + 2) * 2048, (void*)&Vl[sb][wv * 512]);
    asm volatile("s_waitcnt vmcnt(4)" ::: "memory");
    __builtin_amdgcn_s_barrier();
    COMPUTE(mt & 3);
  }
  asm volatile("s_waitcnt vmcnt(2)" ::: "memory");
  __builtin_amdgcn_s_barrier();
  COMPUTE((NT - 2) & 3);
  asm volatile("s_waitcnt vmcnt(0)" ::: "memory");
  __builtin_amdgcn_s_barrier();
  COMPUTE((NT - 1) & 3);

  lp += __shfl_xor(lp, 32);
  if (h == 0) Lp[(size_t)(chunk * NBH + bh) * NHW + q0 + ql] = lp;
  ushort* od = OHp + ((size_t)(chunk * NBH + bh) * NHW + q0) * 64;
#pragma unroll
  for (int r = 0; r < 16; ++r) {
    int qrow = (r & 3) + 8 * (r >> 2) + 4 * h;
    od[(size_t)qrow * 64 + ql] = f2bf(o0[r]);
    od[(size_t)qrow * 64 + 32 + ql] = f2bf(o1[r]);
  }
}

// ---------------- combine partials + head-mean + projection + residual ----------------
__global__ __launch_bounds__(256) void k_proj(const ushort* __restrict__ OHp,
                                              const float* __restrict__ Lp,
                                              const float* __restrict__ PW,
                                              const float* __restrict__ PB,
                                              const float* __restrict__ org,
                                              float* __restrict__ out) {
  __shared__ float Ls[4][4][16];
  __shared__ float linv[4][16];
  __shared__ float Ms[64][17];
  int p0 = blockIdx.x * 16, b = blockIdx.y;
  int t = threadIdx.x;
  {
    int ck = t >> 6, hd = (t >> 4) & 3, p = t & 15;
    Ls[ck][hd][p] = Lp[(size_t)(ck * NBH + b * 4 + hd) * NHW + p0 + p];
  }
  __syncthreads();
  if (t < 64) {
    int hd = t >> 4, p = t & 15;
    linv[hd][p] = 1.f / (Ls[0][hd][p] + Ls[1][hd][p] + Ls[2][hd][p] + Ls[3][hd][p]);
  }
  __syncthreads();
  {
    int p = t >> 4, c4 = (t & 15) * 4;
    float a0 = 0.f, a1 = 0.f, a2 = 0.f, a3 = 0.f;
#pragma unroll
    for (int hd = 0; hd < 4; ++hd) {
      float s0 = 0.f, s1 = 0.f, s2 = 0.f, s3 = 0.f;
#pragma unroll
      for (int ck = 0; ck < 4; ++ck) {
        ushort4 u = *(const ushort4*)&OHp[((size_t)(ck * NBH + b * 4 + hd) * NHW + p0 + p) * 64 + c4];
        s0 += bf2f(u.x); s1 += bf2f(u.y); s2 += bf2f(u.z); s3 += bf2f(u.w);
      }
      float li = linv[hd][p];
      a0 += s0 * li; a1 += s1 * li; a2 += s2 * li; a3 += s3 * li;
    }
    Ms[c4][p] = 0.25f * a0;
    Ms[c4 + 1][p] = 0.25f * a1;
    Ms[c4 + 2][p] = 0.25f * a2;
    Ms[c4 + 3][p] = 0.25f * a3;
  }
  __syncthreads();
  int p = t & 15, og = t >> 4;
  float acc[4];
#pragma unroll
  for (int i = 0; i < 4; ++i) acc[i] = PB[og * 4 + i];
  for (int c = 0; c < 64; ++c) {
    float xr = Ms[c][p];
#pragma unroll
    for (int i = 0; i < 4; ++i) acc[i] += PW[(og * 4 + i) * 64 + c] * xr;
  }
  const float* orgp = org + (size_t)b * NC * NHW + p0 + p;
  float* outp = out + (size_t)b * NC * NHW + p0 + p;
#pragma unroll
  for (int i = 0; i < 4; ++i) {
    int oc = og * 4 + i;
    outp[(size_t)oc * NHW] = orgp[(size_t)oc * NHW] + acc[i];
  }
}

extern "C" void kernel_launch(void* const* d_in, const int* in_sizes, int n_in,
                              void* d_out, int out_size, void* d_ws, size_t ws_size,
                              hipStream_t stream) {
  const float* emb = (const float*)d_in[0];
  const float* lnw = (const float*)d_in[1];
  const float* lnb = (const float*)d_in[2];
  const float* wq  = (const float*)d_in[3];
  const float* wk  = (const float*)d_in[4];
  const float* wv  = (const float*)d_in[5];
  const float* dwq = (const float*)d_in[6];
  const float* dwk = (const float*)d_in[7];
  const float* dwv = (const float*)d_in[8];
  const float* pw  = (const float*)d_in[9];
  const float* pb  = (const float*)d_in[10];
  char* ws = (char*)d_ws;
  float*  G   = (float*)(ws + OB_G);
  float*  SQ  = (float*)(ws + OB_SQ);
  ushort* OHp = (ushort*)(ws + OB_OHP);
  ushort* Qb  = (ushort*)(ws + OB_Q);
  ushort* Kb  = (ushort*)(ws + OB_K);
  ushort* Vb  = (ushort*)(ws + OB_V);
  float*  Lpt = (float*)(ws + OB_L);
  float*  SCp = (float*)(ws + OB_SC);
  float* out = (float*)d_out;

  hipMemsetAsync(G, 0, 532480, stream);
  k_qkv<<<dim3(NH, 12, NB), 256, 0, stream>>>(emb, lnw, lnb, wq, wk, wv, dwq, dwk, dwv,
                                              Qb, Kb, Vb, G, SQ);
  k_scale<<<dim3(NBH), 256, 0, stream>>>(G, SQ, SCp);
  k_attn<<<dim3(1152), 256, 0, stream>>>(Qb, Kb, Vb, SCp, OHp, Lpt);
  k_proj<<<dim3(NHW / 16, NB), 256, 0, stream>>>(OHp, Lpt, pw, pb, emb, out);
}

// Round 13
// 102.562 us; speedup vs baseline: 1.2565x; 1.2565x over previous
//
#include <hip/hip_runtime.h>
#include <hip/hip_bf16.h>
#include <math.h>

#define NB 4
#define NC 64
#define NH 48
#define NW 48
#define NHEADS 4
#define NCH 256
#define NHW 2304
#define NBH 16
#define NCHK 4
#define CHUNK 576
#define NT (CHUNK / 32)

// ws byte offsets. Region [0,18874368) is time-shared:
//   Y (lnconv->dw) -> Gp+SQp (gram->scalep) -> OHp (attn->proj)
#define OB_Y    0ull
#define OB_GP   0ull
#define OB_SQP  4718592ull
#define OB_OHP  0ull
#define OB_Q    18874368ull
#define OB_K    23592960ull
#define OB_V    28311552ull
#define OB_L    33030144ull
#define OB_SS   33619968ull
#define OB_SA   33620480ull

typedef __bf16 bf16x8 __attribute__((ext_vector_type(8)));
typedef float f32x4 __attribute__((ext_vector_type(4)));
typedef float f32x16 __attribute__((ext_vector_type(16)));

__device__ __forceinline__ float bf2f(ushort u) {
  return __uint_as_float(((unsigned)u) << 16);
}
__device__ __forceinline__ ushort f2bf(float f) {
  __hip_bfloat16 h = __float2bfloat16(f);
  return *(ushort*)&h;
}
__device__ __forceinline__ void gload16(const void* g, void* l) {
  __builtin_amdgcn_global_load_lds((const __attribute__((address_space(1))) unsigned int*)g,
                                   (__attribute__((address_space(3))) unsigned int*)l, 16, 0, 0);
}

// ---------------- fused LayerNorm + 1x1 conv as bf16 MFMA GEMM ----------------
__global__ __launch_bounds__(256) void k_lnconv(const float* __restrict__ emb,
                                                const float* __restrict__ lw,
                                                const float* __restrict__ lb,
                                                const float* __restrict__ wq,
                                                const float* __restrict__ wk,
                                                const float* __restrict__ wv,
                                                ushort* __restrict__ Y) {
  __shared__ float Xs[64][68];   // [px][c]
  __shared__ float sp[4][64], ssp[4][64];
  __shared__ float mu_s[64], rs_s[64], lw_s[64], lb_s[64];
  int p0 = blockIdx.x * 64, b = blockIdx.y, qkv = blockIdx.z;
  const float* Wm = qkv == 0 ? wq : (qkv == 1 ? wk : wv);
  const float* src = emb + (size_t)b * NC * NHW + p0;
  int t = threadIdx.x;
  for (int e = t; e < 1024; e += 256) {
    int c = e >> 4, p4 = (e & 15) * 4;
    float4 v = *(const float4*)&src[c * NHW + p4];
    Xs[p4][c] = v.x; Xs[p4 + 1][c] = v.y; Xs[p4 + 2][c] = v.z; Xs[p4 + 3][c] = v.w;
  }
  if (t < 64) { lw_s[t] = lw[t]; lb_s[t] = lb[t]; }
  __syncthreads();
  {
    int px = t & 63, cq = t >> 6;
    float s = 0.f, ss = 0.f;
#pragma unroll
    for (int cc = 0; cc < 16; cc += 4) {
      float4 v = *(const float4*)&Xs[px][cq * 16 + cc];
      s += (v.x + v.y) + (v.z + v.w);
      ss += (v.x * v.x + v.y * v.y) + (v.z * v.z + v.w * v.w);
    }
    sp[cq][px] = s;
    ssp[cq][px] = ss;
  }
  __syncthreads();
  if (t < 64) {
    float s4 = (sp[0][t] + sp[1][t]) + (sp[2][t] + sp[3][t]);
    float ss4 = (ssp[0][t] + ssp[1][t]) + (ssp[2][t] + ssp[3][t]);
    float m = s4 * (1.f / 64.f), va = ss4 * (1.f / 64.f) - m * m;
    mu_s[t] = m;
    rs_s[t] = rsqrtf(va + 1e-5f);
  }
  __syncthreads();
  int lane = t & 63, wvi = t >> 6, ql = lane & 31, h = lane >> 5;
  bf16x8 bfr[2][4];
#pragma unroll
  for (int pb = 0; pb < 2; ++pb) {
    int px = pb * 32 + ql;
    float mu = mu_s[px], rs = rs_s[px];
#pragma unroll
    for (int kc = 0; kc < 4; ++kc) {
      union { bf16x8 v; ushort u[8]; } pk;
#pragma unroll
      for (int j = 0; j < 8; ++j) {
        int c = kc * 16 + h * 8 + j;
        pk.u[j] = f2bf((Xs[px][c] - mu) * rs * lw_s[c] + lb_s[c]);
      }
      bfr[pb][kc] = pk.v;
    }
  }
  bf16x8 afr[2][4];
#pragma unroll
  for (int ob = 0; ob < 2; ++ob) {
    const float* wr = Wm + (size_t)(wvi * 64 + ob * 32 + ql) * 64;
#pragma unroll
    for (int kc = 0; kc < 4; ++kc) {
      float4 w0 = *(const float4*)&wr[kc * 16 + h * 8];
      float4 w1 = *(const float4*)&wr[kc * 16 + h * 8 + 4];
      union { bf16x8 v; ushort u[8]; } pk;
      pk.u[0] = f2bf(w0.x); pk.u[1] = f2bf(w0.y); pk.u[2] = f2bf(w0.z); pk.u[3] = f2bf(w0.w);
      pk.u[4] = f2bf(w1.x); pk.u[5] = f2bf(w1.y); pk.u[6] = f2bf(w1.z); pk.u[7] = f2bf(w1.w);
      afr[ob][kc] = pk.v;
    }
  }
  f32x16 d00 = {}, d01 = {}, d10 = {}, d11 = {};
#pragma unroll
  for (int kc = 0; kc < 4; ++kc) {
    d00 = __builtin_amdgcn_mfma_f32_32x32x16_bf16(afr[0][kc], bfr[0][kc], d00, 0, 0, 0);
    d01 = __builtin_amdgcn_mfma_f32_32x32x16_bf16(afr[0][kc], bfr[1][kc], d01, 0, 0, 0);
    d10 = __builtin_amdgcn_mfma_f32_32x32x16_bf16(afr[1][kc], bfr[0][kc], d10, 0, 0, 0);
    d11 = __builtin_amdgcn_mfma_f32_32x32x16_bf16(afr[1][kc], bfr[1][kc], d11, 0, 0, 0);
  }
  ushort* dst = Y + ((size_t)(qkv * NB + b) * NCH + wvi * 64) * NHW + p0;
#pragma unroll
  for (int r = 0; r < 16; ++r) {
    int row = (r & 3) + 8 * (r >> 2) + 4 * h;
    dst[(size_t)row * NHW + ql] = f2bf(d00[r]);
    dst[(size_t)row * NHW + 32 + ql] = f2bf(d01[r]);
    dst[(size_t)(32 + row) * NHW + ql] = f2bf(d10[r]);
    dst[(size_t)(32 + row) * NHW + 32 + ql] = f2bf(d11[r]);
  }
}

// ---------------- depthwise 3x3, vectorized sliding-window conv ----------------
// Q/K out: [bh][cg=c>>3][n][8] ; V out: [bh][mb=n>>3][c][8]
__global__ __launch_bounds__(256) void k_dw(const ushort* __restrict__ Y,
                                            const float* __restrict__ dwq,
                                            const float* __restrict__ dwk,
                                            const float* __restrict__ dwv,
                                            ushort* __restrict__ Qo,
                                            ushort* __restrict__ Ko,
                                            ushort* __restrict__ Vo) {
  __shared__ ushort Ys[64][3][48];
  __shared__ float Zs[64][50];
  __shared__ float Ks9[64][9];
  __shared__ float Rp[4][48];
  __shared__ float Rs[48];
  int h = blockIdx.x;
  int hd = blockIdx.y & 3, qkv = blockIdx.y >> 2;
  int b = blockIdx.z;
  int bh = b * NHEADS + hd;
  const float* dwp = qkv == 0 ? dwq : (qkv == 1 ? dwk : dwv);
  const ushort* src = Y + ((size_t)(qkv * NB + b) * NCH + hd * 64) * NHW;
  int t = threadIdx.x;
  for (int e = t; e < 576; e += 256) Ks9[e / 9][e % 9] = dwp[(size_t)hd * 576 + e];
  for (int e = t; e < 2304; e += 256) {
    int c = e / 36, rem = e % 36, r = rem / 12, w4 = (rem % 12) * 4;
    int hh = h + r - 1;
    ushort4 v = (hh >= 0 && hh < NH) ? *(const ushort4*)&src[c * NHW + hh * NW + w4]
                                     : make_ushort4(0, 0, 0, 0);
    *(ushort4*)&Ys[c][r][w4] = v;
  }
  __syncthreads();
  for (int e = t; e < 768; e += 256) {
    int c = e / 12, w4 = (e % 12) * 4;
    float acc0 = 0.f, acc1 = 0.f, acc2 = 0.f, acc3 = 0.f;
#pragma unroll
    for (int r = 0; r < 3; ++r) {
      const ushort* row = &Ys[c][r][0];
      int li = w4 >= 4 ? w4 - 4 : 0;
      int ri = w4 <= 40 ? w4 + 4 : 40;
      uint2 L = *(const uint2*)&row[li];
      uint2 M = *(const uint2*)&row[w4];
      uint2 R = *(const uint2*)&row[ri];
      float vm1 = (w4 == 0) ? 0.f : __uint_as_float(L.y & 0xffff0000u);
      float m0 = __uint_as_float(M.x << 16);
      float m1 = __uint_as_float(M.x & 0xffff0000u);
      float m2 = __uint_as_float(M.y << 16);
      float m3 = __uint_as_float(M.y & 0xffff0000u);
      float v4 = (w4 == 44) ? 0.f : __uint_as_float(R.x << 16);
      float k0 = Ks9[c][r * 3], k1 = Ks9[c][r * 3 + 1], k2 = Ks9[c][r * 3 + 2];
      acc0 += vm1 * k0 + m0 * k1 + m1 * k2;
      acc1 += m0 * k0 + m1 * k1 + m2 * k2;
      acc2 += m1 * k0 + m2 * k1 + m3 * k2;
      acc3 += m2 * k0 + m3 * k1 + v4 * k2;
    }
    *(float2*)&Zs[c][w4] = make_float2(acc0, acc1);
    *(float2*)&Zs[c][w4 + 2] = make_float2(acc2, acc3);
  }
  __syncthreads();
  if (qkv < 2) {
    if (t < 192) {
      int cq = t / 48, w = t % 48;
      float ss = 0.f;
#pragma unroll
      for (int i = 0; i < 16; ++i) { float z = Zs[cq * 16 + i][w]; ss += z * z; }
      Rp[cq][w] = ss;
    }
    __syncthreads();
    if (t < 48)
      Rs[t] = 1.f / fmaxf(sqrtf(Rp[0][t] + Rp[1][t] + Rp[2][t] + Rp[3][t]), 1e-12f);
    __syncthreads();
    ushort* dst = (qkv == 0 ? Qo : Ko) + (size_t)bh * NHW * 64;
    for (int e = t; e < 768; e += 256) {
      int w = e >> 4, c4 = (e & 15) * 4;
      float rsc = Rs[w];
      ushort4 u = make_ushort4(f2bf(Zs[c4][w] * rsc), f2bf(Zs[c4 + 1][w] * rsc),
                               f2bf(Zs[c4 + 2][w] * rsc), f2bf(Zs[c4 + 3][w] * rsc));
      *(ushort4*)&dst[((size_t)(c4 >> 3) * NHW + h * NW + w) * 8 + (c4 & 7)] = u;
    }
  } else {
    ushort* dst = Vo + (size_t)bh * NHW * 64;
    for (int e = t; e < 768; e += 256) {
      int c = e / 12, w4 = (e % 12) * 4;
      float4 z = *(const float4*)&Zs[c][w4];
      ushort4 u = make_ushort4(f2bf(z.x), f2bf(z.y), f2bf(z.z), f2bf(z.w));
      *(ushort4*)&dst[((size_t)(h * 6 + (w4 >> 3)) * 64 + c) * 8 + (w4 & 7)] = u;
    }
  }
}

// ---------------- gram partials via MFMA (no atomics, no memset) ----------------
// grid (9, 2, 16). Gp[ns][qk][bh][64][64] f32, SQp[ns][qk][bh][64].
__global__ __launch_bounds__(256) void k_gram(const ushort* __restrict__ Q,
                                              const ushort* __restrict__ K,
                                              float* __restrict__ Gp,
                                              float* __restrict__ SQp) {
  __shared__ ushort Xt[64][72];   // [c][n] bf16
  int ns = blockIdx.x, qk = blockIdx.y, bh = blockIdx.z;
  const ushort* src = (qk ? K : Q) + (size_t)bh * NHW * 64;
  int t = threadIdx.x, lane = t & 63, wv = t >> 6;
  int lr = lane & 15, lg = lane >> 4;
  int ci0 = (wv >> 1) * 32, cj0 = (wv & 1) * 32;
  f32x4 acc[2][2];
#pragma unroll
  for (int i = 0; i < 2; ++i)
#pragma unroll
    for (int j = 0; j < 2; ++j) acc[i][j] = (f32x4){0.f, 0.f, 0.f, 0.f};
  float sq = 0.f;
  for (int it = 0; it < 4; ++it) {
    __syncthreads();
#pragma unroll
    for (int i2 = 0; i2 < 2; ++i2) {
      int n = t & 63, cg = (t >> 6) + 4 * i2;
      union { bf16x8 v; ushort u[8]; } ld;
      ld.v = *(const bf16x8*)&src[((size_t)cg * NHW + ns * 256 + it * 64 + n) * 8];
#pragma unroll
      for (int j = 0; j < 8; ++j) Xt[cg * 8 + j][n] = ld.u[j];
    }
    __syncthreads();
    if (t < 64) {
#pragma unroll
      for (int g = 0; g < 8; ++g) {
        union { bf16x8 v; ushort u[8]; } rd;
        rd.v = *(const bf16x8*)&Xt[t][g * 8];
#pragma unroll
        for (int j = 0; j < 8; ++j) sq += bf2f(rd.u[j]);
      }
    }
#pragma unroll
    for (int kh = 0; kh < 2; ++kh) {
      bf16x8 a0 = *(const bf16x8*)&Xt[ci0 + lr][kh * 32 + lg * 8];
      bf16x8 a1 = *(const bf16x8*)&Xt[ci0 + 16 + lr][kh * 32 + lg * 8];
      bf16x8 b0 = *(const bf16x8*)&Xt[cj0 + lr][kh * 32 + lg * 8];
      bf16x8 b1 = *(const bf16x8*)&Xt[cj0 + 16 + lr][kh * 32 + lg * 8];
      acc[0][0] = __builtin_amdgcn_mfma_f32_16x16x32_bf16(a0, b0, acc[0][0], 0, 0, 0);
      acc[0][1] = __builtin_amdgcn_mfma_f32_16x16x32_bf16(a0, b1, acc[0][1], 0, 0, 0);
      acc[1][0] = __builtin_amdgcn_mfma_f32_16x16x32_bf16(a1, b0, acc[1][0], 0, 0, 0);
      acc[1][1] = __builtin_amdgcn_mfma_f32_16x16x32_bf16(a1, b1, acc[1][1], 0, 0, 0);
    }
  }
  float* g = Gp + ((size_t)(ns * 2 + qk) * NBH + bh) * 4096;
#pragma unroll
  for (int ii = 0; ii < 2; ++ii)
#pragma unroll
    for (int jj = 0; jj < 2; ++jj)
#pragma unroll
      for (int r = 0; r < 4; ++r)
        g[(ci0 + ii * 16 + lg * 4 + r) * 64 + cj0 + jj * 16 + lr] = acc[ii][jj][r];
  if (t < 64) SQp[((size_t)(ns * 2 + qk) * NBH + bh) * 64 + t] = sq;
}

// -------- parallel scale partials: grid (8, 16); SSp[s][bh], SA[bh] --------
__global__ __launch_bounds__(256) void k_scalep(const float* __restrict__ Gp,
                                                const float* __restrict__ SQp,
                                                float* __restrict__ SSp,
                                                float* __restrict__ SA) {
  __shared__ float red[256];
  int s = blockIdx.x, bh = blockIdx.y, t = threadIdx.x;
  int i0 = s * 512 + t * 2;
  float gq0 = 0.f, gq1 = 0.f, gk0 = 0.f, gk1 = 0.f;
#pragma unroll
  for (int ns = 0; ns < 9; ++ns) {
    float2 q = *(const float2*)&Gp[((size_t)(ns * 2 + 0) * NBH + bh) * 4096 + i0];
    float2 k = *(const float2*)&Gp[((size_t)(ns * 2 + 1) * NBH + bh) * 4096 + i0];
    gq0 += q.x; gq1 += q.y; gk0 += k.x; gk1 += k.y;
  }
  red[t] = gq0 * gk0 + gq1 * gk1;
  __syncthreads();
  if (t < 128) red[t] += red[t + 128];
  __syncthreads();
  if (t < 64) {
    float v = red[t] + red[t + 64];
#pragma unroll
    for (int m = 32; m; m >>= 1) v += __shfl_xor(v, m);
    if (t == 0) SSp[s * NBH + bh] = v;
  }
  if (s == 0 && t < 64) {
    float sq_q = 0.f, sq_k = 0.f;
#pragma unroll
    for (int ns = 0; ns < 9; ++ns) {
      sq_q += SQp[((size_t)(ns * 2 + 0) * NBH + bh) * 64 + t];
      sq_k += SQp[((size_t)(ns * 2 + 1) * NBH + bh) * 64 + t];
    }
    float v2 = sq_q * sq_k;
#pragma unroll
    for (int m = 32; m; m >>= 1) v2 += __shfl_xor(v2, m);
    if (t == 0) SA[bh] = v2;
  }
}

// ---------------- flash attention (round-8 config; inline scale) ----------------
// grid (1152); block p -> XCD p%8; XCD g owns bh {2g,2g+1}. 4 waves x 32 q-rows.
// 4 LDS buffers, vmcnt(4) + 1 barrier per tile.
__global__ __launch_bounds__(256, 2) void k_attn(const ushort* __restrict__ Q,
                                                 const ushort* __restrict__ K,
                                                 const ushort* __restrict__ V,
                                                 const float* __restrict__ SSp,
                                                 const float* __restrict__ SA,
                                                 ushort* __restrict__ OHp,
                                                 float* __restrict__ Lp) {
  __shared__ ushort Kl[4][2048];
  __shared__ ushort Vl[4][2048];
  int p = blockIdx.x;
  int gb = p & 7;
  int w = p >> 3;          // 0..143
  int qt = w % 18;
  int rem = w / 18;        // 0..7
  int chunk = rem & 3;
  int bh = gb * 2 + (rem >> 2);
  int t = threadIdx.x, lane = t & 63, wv = t >> 6;
  int ql = lane & 31, h = lane >> 5;
  int q0 = qt * 128 + wv * 32;
  int m00 = chunk * CHUNK;
  const ushort* base = Q + (size_t)bh * NHW * 64;

  // inline scale from partials (uniform scalar math)
  float ssf = 0.f;
#pragma unroll
  for (int s = 0; s < 8; ++s) ssf += SSp[s * NBH + bh];
  float saf = SA[bh];
  const double N2 = (double)NHW * (double)NHW;
  double mean = (double)saf / (N2 * 48.0);
  double ea2 = (double)ssf / (N2 * 2304.0);
  double var = ea2 - mean * mean;
  float sc2 = (float)((1.0 / sqrt(var + 1e-5)) / 48.0 * 1.4426950408889634);

  bf16x8 qfr[4];
#pragma unroll
  for (int kc = 0; kc < 4; ++kc)
    qfr[kc] = *(const bf16x8*)&base[((size_t)(kc * 2 + h) * NHW + q0 + ql) * 8];
  asm volatile("s_waitcnt vmcnt(0)" ::: "memory");

  const ushort* kst = K + (size_t)bh * NHW * 64 + ((size_t)(wv * 2 + h) * NHW + m00 + ql) * 8;
  const ushort* vst = V + (size_t)bh * NHW * 64 + ((size_t)((m00 >> 3) + wv) * 64 + lane) * 8;

  f32x16 o0 = {}, o1 = {};
  float lp = 0.f;

  auto COMPUTE = [&](int cb) {
    bf16x8 ka[4], vb[4];
#pragma unroll
    for (int i = 0; i < 4; ++i)
      ka[i] = *(const bf16x8*)&Kl[cb][(2 * i + h) * 256 + ql * 8];
    vb[0] = *(const bf16x8*)&Vl[cb][h * 512 + ql * 8];
    vb[1] = *(const bf16x8*)&Vl[cb][(2 + h) * 512 + ql * 8];
    vb[2] = *(const bf16x8*)&Vl[cb][h * 512 + (ql + 32) * 8];
    vb[3] = *(const bf16x8*)&Vl[cb][(2 + h) * 512 + (ql + 32) * 8];
    __builtin_amdgcn_s_setprio(1);
    f32x16 s = {};
    s = __builtin_amdgcn_mfma_f32_32x32x16_bf16(ka[0], qfr[0], s, 0, 0, 0);
    s = __builtin_amdgcn_mfma_f32_32x32x16_bf16(ka[1], qfr[1], s, 0, 0, 0);
    s = __builtin_amdgcn_mfma_f32_32x32x16_bf16(ka[2], qfr[2], s, 0, 0, 0);
    s = __builtin_amdgcn_mfma_f32_32x32x16_bf16(ka[3], qfr[3], s, 0, 0, 0);
    __builtin_amdgcn_s_setprio(0);
    float pv[16];
    float l0 = 0.f, l1 = 0.f, l2 = 0.f, l3 = 0.f;
#pragma unroll
    for (int r = 0; r < 16; r += 4) {
      pv[r] = __builtin_exp2f(s[r] * sc2);
      pv[r + 1] = __builtin_exp2f(s[r + 1] * sc2);
      pv[r + 2] = __builtin_exp2f(s[r + 2] * sc2);
      pv[r + 3] = __builtin_exp2f(s[r + 3] * sc2);
      l0 += pv[r]; l1 += pv[r + 1]; l2 += pv[r + 2]; l3 += pv[r + 3];
    }
    lp += (l0 + l1) + (l2 + l3);
    uint u[8];
#pragma unroll
    for (int i = 0; i < 8; ++i)
      asm("v_cvt_pk_bf16_f32 %0, %1, %2" : "=v"(u[i]) : "v"(pv[2 * i]), "v"(pv[2 * i + 1]));
    asm volatile("v_permlane32_swap_b32 %0, %1" : "+v"(u[0]), "+v"(u[2]));
    asm volatile("v_permlane32_swap_b32 %0, %1" : "+v"(u[1]), "+v"(u[3]));
    asm volatile("v_permlane32_swap_b32 %0, %1" : "+v"(u[4]), "+v"(u[6]));
    asm volatile("v_permlane32_swap_b32 %0, %1" : "+v"(u[5]), "+v"(u[7]));
    union { uint uu[4]; bf16x8 v; } pa0, pa1;
    pa0.uu[0] = u[0]; pa0.uu[1] = u[1]; pa0.uu[2] = u[2]; pa0.uu[3] = u[3];
    pa1.uu[0] = u[4]; pa1.uu[1] = u[5]; pa1.uu[2] = u[6]; pa1.uu[3] = u[7];
    __builtin_amdgcn_s_setprio(1);
    o0 = __builtin_amdgcn_mfma_f32_32x32x16_bf16(pa0.v, vb[0], o0, 0, 0, 0);
    o0 = __builtin_amdgcn_mfma_f32_32x32x16_bf16(pa1.v, vb[1], o0, 0, 0, 0);
    o1 = __builtin_amdgcn_mfma_f32_32x32x16_bf16(pa0.v, vb[2], o1, 0, 0, 0);
    o1 = __builtin_amdgcn_mfma_f32_32x32x16_bf16(pa1.v, vb[3], o1, 0, 0, 0);
    __builtin_amdgcn_s_setprio(0);
  };

  gload16(kst, (void*)&Kl[0][wv * 512]);
  gload16(vst, (void*)&Vl[0][wv * 512]);
  gload16(kst + 256, (void*)&Kl[1][wv * 512]);
  gload16(vst + 2048, (void*)&Vl[1][wv * 512]);

  for (int mt = 0; mt < NT - 2; ++mt) {
    int sb = (mt + 2) & 3;
    gload16(kst + (size_t)(mt + 2) * 256, (void*)&Kl[sb][wv * 512]);
    gload16(vst + (size_t)(mt + 2) * 2048, (void*)&Vl[sb][wv * 512]);
    asm volatile("s_waitcnt vmcnt(4)" ::: "memory");
    __builtin_amdgcn_s_barrier();
    COMPUTE(mt & 3);
  }
  asm volatile("s_waitcnt vmcnt(2)" ::: "memory");
  __builtin_amdgcn_s_barrier();
  COMPUTE((NT - 2) & 3);
  asm volatile("s_waitcnt vmcnt(0)" ::: "memory");
  __builtin_amdgcn_s_barrier();
  COMPUTE((NT - 1) & 3);

  lp += __shfl_xor(lp, 32);
  if (h == 0) Lp[(size_t)(chunk * NBH + bh) * NHW + q0 + ql] = lp;
  ushort* od = OHp + ((size_t)(chunk * NBH + bh) * NHW + q0) * 64;
#pragma unroll
  for (int r = 0; r < 16; ++r) {
    int qrow = (r & 3) + 8 * (r >> 2) + 4 * h;
    od[(size_t)qrow * 64 + ql] = f2bf(o0[r]);
    od[(size_t)qrow * 64 + 32 + ql] = f2bf(o1[r]);
  }
}

// ---------------- combine partials + head-mean + projection + residual ----------------
__global__ __launch_bounds__(256) void k_proj(const ushort* __restrict__ OHp,
                                              const float* __restrict__ Lp,
                                              const float* __restrict__ PW,
                                              const float* __restrict__ PB,
                                              const float* __restrict__ org,
                                              float* __restrict__ out) {
  __shared__ float Ls[4][4][16];
  __shared__ float linv[4][16];
  __shared__ float Ms[64][17];
  int p0 = blockIdx.x * 16, b = blockIdx.y;
  int t = threadIdx.x;
  {
    int ck = t >> 6, hd = (t >> 4) & 3, p = t & 15;
    Ls[ck][hd][p] = Lp[(size_t)(ck * NBH + b * 4 + hd) * NHW + p0 + p];
  }
  __syncthreads();
  if (t < 64) {
    int hd = t >> 4, p = t & 15;
    linv[hd][p] = 1.f / (Ls[0][hd][p] + Ls[1][hd][p] + Ls[2][hd][p] + Ls[3][hd][p]);
  }
  __syncthreads();
  {
    int p = t >> 4, c4 = (t & 15) * 4;
    float a0 = 0.f, a1 = 0.f, a2 = 0.f, a3 = 0.f;
#pragma unroll
    for (int hd = 0; hd < 4; ++hd) {
      float s0 = 0.f, s1 = 0.f, s2 = 0.f, s3 = 0.f;
#pragma unroll
      for (int ck = 0; ck < 4; ++ck) {
        ushort4 u = *(const ushort4*)&OHp[((size_t)(ck * NBH + b * 4 + hd) * NHW + p0 + p) * 64 + c4];
        s0 += bf2f(u.x); s1 += bf2f(u.y); s2 += bf2f(u.z); s3 += bf2f(u.w);
      }
      float li = linv[hd][p];
      a0 += s0 * li; a1 += s1 * li; a2 += s2 * li; a3 += s3 * li;
    }
    Ms[c4][p] = 0.25f * a0;
    Ms[c4 + 1][p] = 0.25f * a1;
    Ms[c4 + 2][p] = 0.25f * a2;
    Ms[c4 + 3][p] = 0.25f * a3;
  }
  __syncthreads();
  int p = t & 15, og = t >> 4;
  float acc[4];
#pragma unroll
  for (int i = 0; i < 4; ++i) acc[i] = PB[og * 4 + i];
  for (int c = 0; c < 64; ++c) {
    float xr = Ms[c][p];
#pragma unroll
    for (int i = 0; i < 4; ++i) acc[i] += PW[(og * 4 + i) * 64 + c] * xr;
  }
  const float* orgp = org + (size_t)b * NC * NHW + p0 + p;
  float* outp = out + (size_t)b * NC * NHW + p0 + p;
#pragma unroll
  for (int i = 0; i < 4; ++i) {
    int oc = og * 4 + i;
    outp[(size_t)oc * NHW] = orgp[(size_t)oc * NHW] + acc[i];
  }
}

extern "C" void kernel_launch(void* const* d_in, const int* in_sizes, int n_in,
                              void* d_out, int out_size, void* d_ws, size_t ws_size,
                              hipStream_t stream) {
  const float* emb = (const float*)d_in[0];
  const float* lnw = (const float*)d_in[1];
  const float* lnb = (const float*)d_in[2];
  const float* wq  = (const float*)d_in[3];
  const float* wk  = (const float*)d_in[4];
  const float* wv  = (const float*)d_in[5];
  const float* dwq = (const float*)d_in[6];
  const float* dwk = (const float*)d_in[7];
  const float* dwv = (const float*)d_in[8];
  const float* pw  = (const float*)d_in[9];
  const float* pb  = (const float*)d_in[10];
  char* ws = (char*)d_ws;
  ushort* Y   = (ushort*)(ws + OB_Y);
  float*  Gp  = (float*)(ws + OB_GP);
  float*  SQp = (float*)(ws + OB_SQP);
  ushort* OHp = (ushort*)(ws + OB_OHP);
  ushort* Qb  = (ushort*)(ws + OB_Q);
  ushort* Kb  = (ushort*)(ws + OB_K);
  ushort* Vb  = (ushort*)(ws + OB_V);
  float*  Lpt = (float*)(ws + OB_L);
  float*  SSp = (float*)(ws + OB_SS);
  float*  SAp = (float*)(ws + OB_SA);
  float* out = (float*)d_out;

  k_lnconv<<<dim3(NHW / 64, NB, 3), 256, 0, stream>>>(emb, lnw, lnb, wq, wk, wv, Y);
  k_dw<<<dim3(NH, 12, NB), 256, 0, stream>>>(Y, dwq, dwk, dwv, Qb, Kb, Vb);
  k_gram<<<dim3(9, 2, NBH), 256, 0, stream>>>(Qb, Kb, Gp, SQp);
  k_scalep<<<dim3(8, NBH), 256, 0, stream>>>(Gp, SQp, SSp, SAp);
  k_attn<<<dim3(1152), 256, 0, stream>>>(Qb, Kb, Vb, SSp, SAp, OHp, Lpt);
  k_proj<<<dim3(NHW / 16, NB), 256, 0, stream>>>(OHp, Lpt, pw, pb, emb, out);
}

// Round 14
// 98.511 us; speedup vs baseline: 1.3082x; 1.0411x over previous
//
#include <hip/hip_runtime.h>
#include <hip/hip_bf16.h>
#include <math.h>

#define NB 4
#define NC 64
#define NH 48
#define NW 48
#define NHEADS 4
#define NCH 256
#define NHW 2304
#define NBH 16
#define NCHK 4
#define CHUNK 576
#define NT (CHUNK / 32)

// ws byte offsets. Gp+SQp (gram->scalep) and OHp (attn->proj) time-share [0,18.9MB).
#define OB_GP   0ull
#define OB_SQP  4718592ull
#define OB_OHP  0ull
#define OB_Q    18874368ull
#define OB_K    23592960ull
#define OB_V    28311552ull
#define OB_L    33030144ull
#define OB_SS   33619968ull
#define OB_SA   33620480ull

typedef __bf16 bf16x8 __attribute__((ext_vector_type(8)));
typedef float f32x4 __attribute__((ext_vector_type(4)));
typedef float f32x16 __attribute__((ext_vector_type(16)));

__device__ __forceinline__ float bf2f(ushort u) {
  return __uint_as_float(((unsigned)u) << 16);
}
__device__ __forceinline__ ushort f2bf(float f) {
  __hip_bfloat16 h = __float2bfloat16(f);
  return *(ushort*)&h;
}
__device__ __forceinline__ void gload16(const void* g, void* l) {
  __builtin_amdgcn_global_load_lds((const __attribute__((address_space(1))) unsigned int*)g,
                                   (__attribute__((address_space(3))) unsigned int*)l, 16, 0, 0);
}

// ========== fused LN + 1x1conv(MFMA) + dw3x3 + L2norm, one kernel ==========
// grid (48, 12, NB): blockIdx.y = hd + 4*qkv. 256 thr. LDS 38.5KB -> 4 blocks/CU.
// Eb bf16 [144 px][72] (16B-chunk XOR swizzle chunk'=(c>>3)^((px>>3)&7)); raw ->
// normalized in place -> (after GEMM) overlaid by Yl bf16 [64 ch][148 px].
#define DF_ZS 20736
#define DF_K9 33536
#define DF_RP 35840
#define DF_RS 36608
#define DF_MU 36800
#define DF_RSD 37376
#define DF_LW 37952
#define DF_LB 38208
__global__ __launch_bounds__(256) void k_dwf(const float* __restrict__ emb,
                                             const float* __restrict__ lw,
                                             const float* __restrict__ lb,
                                             const float* __restrict__ wq,
                                             const float* __restrict__ wk,
                                             const float* __restrict__ wv,
                                             const float* __restrict__ dwq,
                                             const float* __restrict__ dwk,
                                             const float* __restrict__ dwv,
                                             ushort* __restrict__ Qo,
                                             ushort* __restrict__ Ko,
                                             ushort* __restrict__ Vo) {
  __shared__ __align__(16) char pool[38464];
  ushort* Eb = (ushort*)pool;              // [144][72] swizzled -> Yl [64][148]
  ushort* Yl = (ushort*)pool;
  float* Zs = (float*)(pool + DF_ZS);      // [64][50]
  float* Ks9 = (float*)(pool + DF_K9);     // [64][9]
  float* Rp = (float*)(pool + DF_RP);      // [4][48]
  float* Rs = (float*)(pool + DF_RS);      // [48]
  float* mu_s = (float*)(pool + DF_MU);    // [144]
  float* rs_s = (float*)(pool + DF_RSD);   // [144]
  float* lw_s = (float*)(pool + DF_LW);
  float* lb_s = (float*)(pool + DF_LB);

  int h = blockIdx.x;
  int hd = blockIdx.y & 3, qkv = blockIdx.y >> 2;
  int b = blockIdx.z;
  int bh = b * NHEADS + hd;
  const float* Wm = qkv == 0 ? wq : (qkv == 1 ? wk : wv);
  const float* dwp = qkv == 0 ? dwq : (qkv == 1 ? dwk : dwv);
  int t = threadIdx.x, lane = t & 63, wvi = t >> 6;
  int l15 = lane & 15, l4 = lane >> 4;

  // phase 1: stage emb rows h-1..h+1 as raw bf16 into Eb (swizzled); lw/lb; Ks9
  for (int e = t; e < 2304; e += 256) {
    int c = e / 36, rem = e % 36, r = rem / 12, w4 = (rem % 12) * 4;
    int hh = h + r - 1;
    float4 v = (hh >= 0 && hh < NH)
                   ? *(const float4*)&emb[((size_t)b * NC + c) * NHW + hh * NW + w4]
                   : make_float4(0.f, 0.f, 0.f, 0.f);
    int c8 = c >> 3, cl = c & 7;
    float vv[4] = {v.x, v.y, v.z, v.w};
#pragma unroll
    for (int i = 0; i < 4; ++i) {
      int px = r * 48 + w4 + i;
      int ch = c8 ^ ((px >> 3) & 7);
      Eb[px * 72 + ch * 8 + cl] = f2bf(vv[i]);
    }
  }
  if (t < 64) { lw_s[t] = lw[t]; lb_s[t] = lb[t]; }
  for (int e = t; e < 576; e += 256) Ks9[e] = dwp[(size_t)hd * 576 + e];
  __syncthreads();
  // phase 2: LN stats per px (row b128 reads)
  if (t < 144) {
    int xp = (t >> 3) & 7;
    float s = 0.f, ss = 0.f;
#pragma unroll
    for (int c8 = 0; c8 < 8; ++c8) {
      union { bf16x8 v; ushort u[8]; } rd;
      rd.v = *(const bf16x8*)&Eb[t * 72 + (c8 ^ xp) * 8];
#pragma unroll
      for (int j = 0; j < 8; ++j) { float v = bf2f(rd.u[j]); s += v; ss += v * v; }
    }
    float m = s * (1.f / 64.f), va = ss * (1.f / 64.f) - m * m;
    mu_s[t] = m;
    rs_s[t] = rsqrtf(va + 1e-5f);
  }
  __syncthreads();
  // phase 3: normalize in place (per-row)
  if (t < 144) {
    int xp = (t >> 3) & 7;
    float mu = mu_s[t], rs = rs_s[t];
#pragma unroll
    for (int c8 = 0; c8 < 8; ++c8) {
      ushort* ptr = &Eb[t * 72 + (c8 ^ xp) * 8];
      union { bf16x8 v; ushort u[8]; } rd;
      rd.v = *(const bf16x8*)ptr;
#pragma unroll
      for (int j = 0; j < 8; ++j) {
        int c = c8 * 8 + j;
        rd.u[j] = f2bf((bf2f(rd.u[j]) - mu) * rs * lw_s[c] + lb_s[c]);
      }
      *(bf16x8*)ptr = rd.v;
    }
  }
  __syncthreads();
  // phase 4: GEMM 64ch x 144px x 64c via 16x16x32; wave wvi -> chs [16wvi,16wvi+16)
  f32x4 acc[9];
#pragma unroll
  for (int i = 0; i < 9; ++i) acc[i] = (f32x4){0.f, 0.f, 0.f, 0.f};
  {
    bf16x8 afr[2];
    const float* wr = Wm + (size_t)(hd * 64 + wvi * 16 + l15) * 64;
#pragma unroll
    for (int kc = 0; kc < 2; ++kc) {
      float4 w0 = *(const float4*)&wr[kc * 32 + l4 * 8];
      float4 w1 = *(const float4*)&wr[kc * 32 + l4 * 8 + 4];
      union { bf16x8 v; ushort u[8]; } pk;
      pk.u[0] = f2bf(w0.x); pk.u[1] = f2bf(w0.y); pk.u[2] = f2bf(w0.z); pk.u[3] = f2bf(w0.w);
      pk.u[4] = f2bf(w1.x); pk.u[5] = f2bf(w1.y); pk.u[6] = f2bf(w1.z); pk.u[7] = f2bf(w1.w);
      afr[kc] = pk.v;
    }
#pragma unroll
    for (int pxt = 0; pxt < 9; ++pxt) {
      int px = pxt * 16 + l15;
      int xp = (px >> 3) & 7;
#pragma unroll
      for (int kc = 0; kc < 2; ++kc) {
        int c8 = kc * 4 + l4;
        bf16x8 bfr = *(const bf16x8*)&Eb[px * 72 + (c8 ^ xp) * 8];
        acc[pxt] = __builtin_amdgcn_mfma_f32_16x16x32_bf16(afr[kc], bfr, acc[pxt], 0, 0, 0);
      }
    }
  }
  __syncthreads();   // all Eb reads done; Yl overlays
  // phase 5: write Yl [ch][148]
#pragma unroll
  for (int pxt = 0; pxt < 9; ++pxt)
#pragma unroll
    for (int r = 0; r < 4; ++r)
      Yl[(wvi * 16 + l4 * 4 + r) * 148 + pxt * 16 + l15] = f2bf(acc[pxt][r]);
  __syncthreads();
  // phase 6: depthwise 3x3 (row-validity via zeroed weights) -> Zs
  for (int e = t; e < 768; e += 256) {
    int c = e / 12, w4 = (e % 12) * 4;
    float acc0 = 0.f, acc1 = 0.f, acc2 = 0.f, acc3 = 0.f;
#pragma unroll
    for (int r = 0; r < 3; ++r) {
      bool rOK = (unsigned)(h + r - 1) < (unsigned)NH;
      const ushort* row = &Yl[c * 148 + r * 48];
      int li = w4 >= 4 ? w4 - 4 : 0;
      int ri = w4 <= 40 ? w4 + 4 : 40;
      uint2 L = *(const uint2*)&row[li];
      uint2 M = *(const uint2*)&row[w4];
      uint2 R = *(const uint2*)&row[ri];
      float vm1 = (w4 == 0) ? 0.f : __uint_as_float(L.y & 0xffff0000u);
      float m0 = __uint_as_float(M.x << 16);
      float m1 = __uint_as_float(M.x & 0xffff0000u);
      float m2 = __uint_as_float(M.y << 16);
      float m3 = __uint_as_float(M.y & 0xffff0000u);
      float v4 = (w4 == 44) ? 0.f : __uint_as_float(R.x << 16);
      float k0 = rOK ? Ks9[c * 9 + r * 3] : 0.f;
      float k1 = rOK ? Ks9[c * 9 + r * 3 + 1] : 0.f;
      float k2 = rOK ? Ks9[c * 9 + r * 3 + 2] : 0.f;
      acc0 += vm1 * k0 + m0 * k1 + m1 * k2;
      acc1 += m0 * k0 + m1 * k1 + m2 * k2;
      acc2 += m1 * k0 + m2 * k1 + m3 * k2;
      acc3 += m2 * k0 + m3 * k1 + v4 * k2;
    }
    *(float2*)&Zs[c * 50 + w4] = make_float2(acc0, acc1);
    *(float2*)&Zs[c * 50 + w4 + 2] = make_float2(acc2, acc3);
  }
  __syncthreads();
  if (qkv < 2) {
    if (t < 192) {
      int cq = t / 48, w = t % 48;
      float ss = 0.f;
#pragma unroll
      for (int i = 0; i < 16; ++i) { float z = Zs[(cq * 16 + i) * 50 + w]; ss += z * z; }
      Rp[cq * 48 + w] = ss;
    }
    __syncthreads();
    if (t < 48)
      Rs[t] = 1.f / fmaxf(sqrtf(Rp[t] + Rp[48 + t] + Rp[96 + t] + Rp[144 + t]), 1e-12f);
    __syncthreads();
    ushort* dst = (qkv == 0 ? Qo : Ko) + (size_t)bh * NHW * 64;
    for (int e = t; e < 768; e += 256) {
      int w = e >> 4, c4 = (e & 15) * 4;
      float rsc = Rs[w];
      ushort4 u = make_ushort4(f2bf(Zs[c4 * 50 + w] * rsc), f2bf(Zs[(c4 + 1) * 50 + w] * rsc),
                               f2bf(Zs[(c4 + 2) * 50 + w] * rsc), f2bf(Zs[(c4 + 3) * 50 + w] * rsc));
      *(ushort4*)&dst[((size_t)(c4 >> 3) * NHW + h * NW + w) * 8 + (c4 & 7)] = u;
    }
  } else {
    ushort* dst = Vo + (size_t)bh * NHW * 64;
    for (int e = t; e < 768; e += 256) {
      int c = e / 12, w4 = (e % 12) * 4;
      float4 z = *(const float4*)&Zs[c * 50 + w4];
      ushort4 u = make_ushort4(f2bf(z.x), f2bf(z.y), f2bf(z.z), f2bf(z.w));
      *(ushort4*)&dst[((size_t)(h * 6 + (w4 >> 3)) * 64 + c) * 8 + (w4 & 7)] = u;
    }
  }
}

// ---------------- gram partials via MFMA (no atomics, no memset) ----------------
__global__ __launch_bounds__(256) void k_gram(const ushort* __restrict__ Q,
                                              const ushort* __restrict__ K,
                                              float* __restrict__ Gp,
                                              float* __restrict__ SQp) {
  __shared__ ushort Xt[64][72];   // [c][n] bf16
  int ns = blockIdx.x, qk = blockIdx.y, bh = blockIdx.z;
  const ushort* src = (qk ? K : Q) + (size_t)bh * NHW * 64;
  int t = threadIdx.x, lane = t & 63, wv = t >> 6;
  int lr = lane & 15, lg = lane >> 4;
  int ci0 = (wv >> 1) * 32, cj0 = (wv & 1) * 32;
  f32x4 acc[2][2];
#pragma unroll
  for (int i = 0; i < 2; ++i)
#pragma unroll
    for (int j = 0; j < 2; ++j) acc[i][j] = (f32x4){0.f, 0.f, 0.f, 0.f};
  float sq = 0.f;
  for (int it = 0; it < 4; ++it) {
    __syncthreads();
#pragma unroll
    for (int i2 = 0; i2 < 2; ++i2) {
      int n = t & 63, cg = (t >> 6) + 4 * i2;
      union { bf16x8 v; ushort u[8]; } ld;
      ld.v = *(const bf16x8*)&src[((size_t)cg * NHW + ns * 256 + it * 64 + n) * 8];
#pragma unroll
      for (int j = 0; j < 8; ++j) Xt[cg * 8 + j][n] = ld.u[j];
    }
    __syncthreads();
    if (t < 64) {
#pragma unroll
      for (int g = 0; g < 8; ++g) {
        union { bf16x8 v; ushort u[8]; } rd;
        rd.v = *(const bf16x8*)&Xt[t][g * 8];
#pragma unroll
        for (int j = 0; j < 8; ++j) sq += bf2f(rd.u[j]);
      }
    }
#pragma unroll
    for (int kh = 0; kh < 2; ++kh) {
      bf16x8 a0 = *(const bf16x8*)&Xt[ci0 + lr][kh * 32 + lg * 8];
      bf16x8 a1 = *(const bf16x8*)&Xt[ci0 + 16 + lr][kh * 32 + lg * 8];
      bf16x8 b0 = *(const bf16x8*)&Xt[cj0 + lr][kh * 32 + lg * 8];
      bf16x8 b1 = *(const bf16x8*)&Xt[cj0 + 16 + lr][kh * 32 + lg * 8];
      acc[0][0] = __builtin_amdgcn_mfma_f32_16x16x32_bf16(a0, b0, acc[0][0], 0, 0, 0);
      acc[0][1] = __builtin_amdgcn_mfma_f32_16x16x32_bf16(a0, b1, acc[0][1], 0, 0, 0);
      acc[1][0] = __builtin_amdgcn_mfma_f32_16x16x32_bf16(a1, b0, acc[1][0], 0, 0, 0);
      acc[1][1] = __builtin_amdgcn_mfma_f32_16x16x32_bf16(a1, b1, acc[1][1], 0, 0, 0);
    }
  }
  float* g = Gp + ((size_t)(ns * 2 + qk) * NBH + bh) * 4096;
#pragma unroll
  for (int ii = 0; ii < 2; ++ii)
#pragma unroll
    for (int jj = 0; jj < 2; ++jj)
#pragma unroll
      for (int r = 0; r < 4; ++r)
        g[(ci0 + ii * 16 + lg * 4 + r) * 64 + cj0 + jj * 16 + lr] = acc[ii][jj][r];
  if (t < 64) SQp[((size_t)(ns * 2 + qk) * NBH + bh) * 64 + t] = sq;
}

// -------- parallel scale partials: grid (8, 16); SSp[s][bh], SA[bh] --------
__global__ __launch_bounds__(256) void k_scalep(const float* __restrict__ Gp,
                                                const float* __restrict__ SQp,
                                                float* __restrict__ SSp,
                                                float* __restrict__ SA) {
  __shared__ float red[256];
  int s = blockIdx.x, bh = blockIdx.y, t = threadIdx.x;
  int i0 = s * 512 + t * 2;
  float gq0 = 0.f, gq1 = 0.f, gk0 = 0.f, gk1 = 0.f;
#pragma unroll
  for (int ns = 0; ns < 9; ++ns) {
    float2 q = *(const float2*)&Gp[((size_t)(ns * 2 + 0) * NBH + bh) * 4096 + i0];
    float2 k = *(const float2*)&Gp[((size_t)(ns * 2 + 1) * NBH + bh) * 4096 + i0];
    gq0 += q.x; gq1 += q.y; gk0 += k.x; gk1 += k.y;
  }
  red[t] = gq0 * gk0 + gq1 * gk1;
  __syncthreads();
  if (t < 128) red[t] += red[t + 128];
  __syncthreads();
  if (t < 64) {
    float v = red[t] + red[t + 64];
#pragma unroll
    for (int m = 32; m; m >>= 1) v += __shfl_xor(v, m);
    if (t == 0) SSp[s * NBH + bh] = v;
  }
  if (s == 0 && t < 64) {
    float sq_q = 0.f, sq_k = 0.f;
#pragma unroll
    for (int ns = 0; ns < 9; ++ns) {
      sq_q += SQp[((size_t)(ns * 2 + 0) * NBH + bh) * 64 + t];
      sq_k += SQp[((size_t)(ns * 2 + 1) * NBH + bh) * 64 + t];
    }
    float v2 = sq_q * sq_k;
#pragma unroll
    for (int m = 32; m; m >>= 1) v2 += __shfl_xor(v2, m);
    if (t == 0) SA[bh] = v2;
  }
}

// ---------------- flash attention (round-8 config; inline scale) ----------------
__global__ __launch_bounds__(256, 2) void k_attn(const ushort* __restrict__ Q,
                                                 const ushort* __restrict__ K,
                                                 const ushort* __restrict__ V,
                                                 const float* __restrict__ SSp,
                                                 const float* __restrict__ SA,
                                                 ushort* __restrict__ OHp,
                                                 float* __restrict__ Lp) {
  __shared__ ushort Kl[4][2048];
  __shared__ ushort Vl[4][2048];
  int p = blockIdx.x;
  int gb = p & 7;
  int w = p >> 3;          // 0..143
  int qt = w % 18;
  int rem = w / 18;        // 0..7
  int chunk = rem & 3;
  int bh = gb * 2 + (rem >> 2);
  int t = threadIdx.x, lane = t & 63, wv = t >> 6;
  int ql = lane & 31, h = lane >> 5;
  int q0 = qt * 128 + wv * 32;
  int m00 = chunk * CHUNK;
  const ushort* base = Q + (size_t)bh * NHW * 64;

  float ssf = 0.f;
#pragma unroll
  for (int s = 0; s < 8; ++s) ssf += SSp[s * NBH + bh];
  float saf = SA[bh];
  const double N2 = (double)NHW * (double)NHW;
  double mean = (double)saf / (N2 * 48.0);
  double ea2 = (double)ssf / (N2 * 2304.0);
  double var = ea2 - mean * mean;
  float sc2 = (float)((1.0 / sqrt(var + 1e-5)) / 48.0 * 1.4426950408889634);

  bf16x8 qfr[4];
#pragma unroll
  for (int kc = 0; kc < 4; ++kc)
    qfr[kc] = *(const bf16x8*)&base[((size_t)(kc * 2 + h) * NHW + q0 + ql) * 8];
  asm volatile("s_waitcnt vmcnt(0)" ::: "memory");

  const ushort* kst = K + (size_t)bh * NHW * 64 + ((size_t)(wv * 2 + h) * NHW + m00 + ql) * 8;
  const ushort* vst = V + (size_t)bh * NHW * 64 + ((size_t)((m00 >> 3) + wv) * 64 + lane) * 8;

  f32x16 o0 = {}, o1 = {};
  float lp = 0.f;

  auto COMPUTE = [&](int cb) {
    bf16x8 ka[4], vb[4];
#pragma unroll
    for (int i = 0; i < 4; ++i)
      ka[i] = *(const bf16x8*)&Kl[cb][(2 * i + h) * 256 + ql * 8];
    vb[0] = *(const bf16x8*)&Vl[cb][h * 512 + ql * 8];
    vb[1] = *(const bf16x8*)&Vl[cb][(2 + h) * 512 + ql * 8];
    vb[2] = *(const bf16x8*)&Vl[cb][h * 512 + (ql + 32) * 8];
    vb[3] = *(const bf16x8*)&Vl[cb][(2 + h) * 512 + (ql + 32) * 8];
    __builtin_amdgcn_s_setprio(1);
    f32x16 s = {};
    s = __builtin_amdgcn_mfma_f32_32x32x16_bf16(ka[0], qfr[0], s, 0, 0, 0);
    s = __builtin_amdgcn_mfma_f32_32x32x16_bf16(ka[1], qfr[1], s, 0, 0, 0);
    s = __builtin_amdgcn_mfma_f32_32x32x16_bf16(ka[2], qfr[2], s, 0, 0, 0);
    s = __builtin_amdgcn_mfma_f32_32x32x16_bf16(ka[3], qfr[3], s, 0, 0, 0);
    __builtin_amdgcn_s_setprio(0);
    float pv[16];
    float l0 = 0.f, l1 = 0.f, l2 = 0.f, l3 = 0.f;
#pragma unroll
    for (int r = 0; r < 16; r += 4) {
      pv[r] = __builtin_exp2f(s[r] * sc2);
      pv[r + 1] = __builtin_exp2f(s[r + 1] * sc2);
      pv[r + 2] = __builtin_exp2f(s[r + 2] * sc2);
      pv[r + 3] = __builtin_exp2f(s[r + 3] * sc2);
      l0 += pv[r]; l1 += pv[r + 1]; l2 += pv[r + 2]; l3 += pv[r + 3];
    }
    lp += (l0 + l1) + (l2 + l3);
    uint u[8];
#pragma unroll
    for (int i = 0; i < 8; ++i)
      asm("v_cvt_pk_bf16_f32 %0, %1, %2" : "=v"(u[i]) : "v"(pv[2 * i]), "v"(pv[2 * i + 1]));
    asm volatile("v_permlane32_swap_b32 %0, %1" : "+v"(u[0]), "+v"(u[2]));
    asm volatile("v_permlane32_swap_b32 %0, %1" : "+v"(u[1]), "+v"(u[3]));
    asm volatile("v_permlane32_swap_b32 %0, %1" : "+v"(u[4]), "+v"(u[6]));
    asm volatile("v_permlane32_swap_b32 %0, %1" : "+v"(u[5]), "+v"(u[7]));
    union { uint uu[4]; bf16x8 v; } pa0, pa1;
    pa0.uu[0] = u[0]; pa0.uu[1] = u[1]; pa0.uu[2] = u[2]; pa0.uu[3] = u[3];
    pa1.uu[0] = u[4]; pa1.uu[1] = u[5]; pa1.uu[2] = u[6]; pa1.uu[3] = u[7];
    __builtin_amdgcn_s_setprio(1);
    o0 = __builtin_amdgcn_mfma_f32_32x32x16_bf16(pa0.v, vb[0], o0, 0, 0, 0);
    o0 = __builtin_amdgcn_mfma_f32_32x32x16_bf16(pa1.v, vb[1], o0, 0, 0, 0);
    o1 = __builtin_amdgcn_mfma_f32_32x32x16_bf16(pa0.v, vb[2], o1, 0, 0, 0);
    o1 = __builtin_amdgcn_mfma_f32_32x32x16_bf16(pa1.v, vb[3], o1, 0, 0, 0);
    __builtin_amdgcn_s_setprio(0);
  };

  gload16(kst, (void*)&Kl[0][wv * 512]);
  gload16(vst, (void*)&Vl[0][wv * 512]);
  gload16(kst + 256, (void*)&Kl[1][wv * 512]);
  gload16(vst + 2048, (void*)&Vl[1][wv * 512]);

  for (int mt = 0; mt < NT - 2; ++mt) {
    int sb = (mt + 2) & 3;
    gload16(kst + (size_t)(mt + 2) * 256, (void*)&Kl[sb][wv * 512]);
    gload16(vst + (size_t)(mt + 2) * 2048, (void*)&Vl[sb][wv * 512]);
    asm volatile("s_waitcnt vmcnt(4)" ::: "memory");
    __builtin_amdgcn_s_barrier();
    COMPUTE(mt & 3);
  }
  asm volatile("s_waitcnt vmcnt(2)" ::: "memory");
  __builtin_amdgcn_s_barrier();
  COMPUTE((NT - 2) & 3);
  asm volatile("s_waitcnt vmcnt(0)" ::: "memory");
  __builtin_amdgcn_s_barrier();
  COMPUTE((NT - 1) & 3);

  lp += __shfl_xor(lp, 32);
  if (h == 0) Lp[(size_t)(chunk * NBH + bh) * NHW + q0 + ql] = lp;
  ushort* od = OHp + ((size_t)(chunk * NBH + bh) * NHW + q0) * 64;
#pragma unroll
  for (int r = 0; r < 16; ++r) {
    int qrow = (r & 3) + 8 * (r >> 2) + 4 * h;
    od[(size_t)qrow * 64 + ql] = f2bf(o0[r]);
    od[(size_t)qrow * 64 + 32 + ql] = f2bf(o1[r]);
  }
}

// ---------------- combine partials + head-mean + projection + residual ----------------
__global__ __launch_bounds__(256) void k_proj(const ushort* __restrict__ OHp,
                                              const float* __restrict__ Lp,
                                              const float* __restrict__ PW,
                                              const float* __restrict__ PB,
                                              const float* __restrict__ org,
                                              float* __restrict__ out) {
  __shared__ float Ls[4][4][16];
  __shared__ float linv[4][16];
  __shared__ float Ms[64][17];
  int p0 = blockIdx.x * 16, b = blockIdx.y;
  int t = threadIdx.x;
  {
    int ck = t >> 6, hd = (t >> 4) & 3, p = t & 15;
    Ls[ck][hd][p] = Lp[(size_t)(ck * NBH + b * 4 + hd) * NHW + p0 + p];
  }
  __syncthreads();
  if (t < 64) {
    int hd = t >> 4, p = t & 15;
    linv[hd][p] = 1.f / (Ls[0][hd][p] + Ls[1][hd][p] + Ls[2][hd][p] + Ls[3][hd][p]);
  }
  __syncthreads();
  {
    int p = t >> 4, c4 = (t & 15) * 4;
    float a0 = 0.f, a1 = 0.f, a2 = 0.f, a3 = 0.f;
#pragma unroll
    for (int hd = 0; hd < 4; ++hd) {
      float s0 = 0.f, s1 = 0.f, s2 = 0.f, s3 = 0.f;
#pragma unroll
      for (int ck = 0; ck < 4; ++ck) {
        ushort4 u = *(const ushort4*)&OHp[((size_t)(ck * NBH + b * 4 + hd) * NHW + p0 + p) * 64 + c4];
        s0 += bf2f(u.x); s1 += bf2f(u.y); s2 += bf2f(u.z); s3 += bf2f(u.w);
      }
      float li = linv[hd][p];
      a0 += s0 * li; a1 += s1 * li; a2 += s2 * li; a3 += s3 * li;
    }
    Ms[c4][p] = 0.25f * a0;
    Ms[c4 + 1][p] = 0.25f * a1;
    Ms[c4 + 2][p] = 0.25f * a2;
    Ms[c4 + 3][p] = 0.25f * a3;
  }
  __syncthreads();
  int p = t & 15, og = t >> 4;
  float acc[4];
#pragma unroll
  for (int i = 0; i < 4; ++i) acc[i] = PB[og * 4 + i];
  for (int c = 0; c < 64; ++c) {
    float xr = Ms[c][p];
#pragma unroll
    for (int i = 0; i < 4; ++i) acc[i] += PW[(og * 4 + i) * 64 + c] * xr;
  }
  const float* orgp = org + (size_t)b * NC * NHW + p0 + p;
  float* outp = out + (size_t)b * NC * NHW + p0 + p;
#pragma unroll
  for (int i = 0; i < 4; ++i) {
    int oc = og * 4 + i;
    outp[(size_t)oc * NHW] = orgp[(size_t)oc * NHW] + acc[i];
  }
}

extern "C" void kernel_launch(void* const* d_in, const int* in_sizes, int n_in,
                              void* d_out, int out_size, void* d_ws, size_t ws_size,
                              hipStream_t stream) {
  const float* emb = (const float*)d_in[0];
  const float* lnw = (const float*)d_in[1];
  const float* lnb = (const float*)d_in[2];
  const float* wq  = (const float*)d_in[3];
  const float* wk  = (const float*)d_in[4];
  const float* wv  = (const float*)d_in[5];
  const float* dwq = (const float*)d_in[6];
  const float* dwk = (const float*)d_in[7];
  const float* dwv = (const float*)d_in[8];
  const float* pw  = (const float*)d_in[9];
  const float* pb  = (const float*)d_in[10];
  char* ws = (char*)d_ws;
  float*  Gp  = (float*)(ws + OB_GP);
  float*  SQp = (float*)(ws + OB_SQP);
  ushort* OHp = (ushort*)(ws + OB_OHP);
  ushort* Qb  = (ushort*)(ws + OB_Q);
  ushort* Kb  = (ushort*)(ws + OB_K);
  ushort* Vb  = (ushort*)(ws + OB_V);
  float*  Lpt = (float*)(ws + OB_L);
  float*  SSp = (float*)(ws + OB_SS);
  float*  SAp = (float*)(ws + OB_SA);
  float* out = (float*)d_out;

  k_dwf<<<dim3(NH, 12, NB), 256, 0, stream>>>(emb, lnw, lnb, wq, wk, wv, dwq, dwk, dwv,
                                              Qb, Kb, Vb);
  k_gram<<<dim3(9, 2, NBH), 256, 0, stream>>>(Qb, Kb, Gp, SQp);
  k_scalep<<<dim3(8, NBH), 256, 0, stream>>>(Gp, SQp, SSp, SAp);
  k_attn<<<dim3(1152), 256, 0, stream>>>(Qb, Kb, Vb, SSp, SAp, OHp, Lpt);
  k_proj<<<dim3(NHW / 16, NB), 256, 0, stream>>>(OHp, Lpt, pw, pb, emb, out);
}